// Round 5
// baseline (478.170 us; speedup 1.0000x reference)
//
#include <hip/hip_runtime.h>

// KANLayer: B=1024, I=64, O=64, H=32. ALL I/O float32 (per reference).
// out[b,o] = sum_i [ bw[o,i]*leaky(x[b,i]) + lw[o,i]*( sum_k W3[o,i,k]*h2[k] + b3[o,i] ) ]
//   h1[h] = leaky(x[b,i]*W1[o,i,h] + b1[o,i,h])
//   h2[k] = leaky(sum_h h1[h]*W2[o,i,k,h] + b2[o,i,k])
//
// R17: shrink the instruction stream (R16 refuted occupancy-as-lever: 50%
// occ but 72us, VALUBusy 30% — splitting work ADDED VALU: repack amortizes
// over MT). Evidence ws is big: harness fillBuffer poisons 268MB = d_ws.
// (1) kan_pre -> d_ws: W2 repacked to f16 in MFMA-fragment order (8.4MB,
//     kills 16 pkrtz/ii/wave + halves W2 bytes); q[o,i,h] = .505*lw*
//     sum_k w3_k*W2[k,h] (f16) + rbias = .505*lw*sum_k w3_k*b2_k, folding
//     the positive leaky half into a 3rd MFMA (B=broadcast q, C-in=running
//     acc1) -> epilogue 16 FMA/m -> 8 FMA/m (only |c| terms).
//     leaky(v)*w = (.505w)*v + (.495w)*|v|; sum_k(.505w_k)c[r,k] =
//     sum_h h1[r,h]*q[h] + rbias  (c includes b2 via MFMA C-in).
// (2) main = R13 skeleton (256thr, ROWS=64, MT=4, grid (64,16), the
//     never-spilled regime, launch_bounds(256,4) cap 128). Per-ii VALU
//     112 -> ~70, chains much shorter; W2 f16 direct halfx8 loads with
//     2-deep register prefetch. wbs pairs now (nn=.495*lw*w3, b2).
// (3) ws_size guarded; R16 kernel kept verbatim as fallback.
// Verify order: WRITE_SIZE(main) ~2MB (no spill), VGPR 85-100, then
// dur: pre ~10us + main 20-28us (was 43).

#define H_   32
#define NI   64
#define NO   64
#define NB   1024
#define ROWS 64     // batch rows per block (4 m-tiles)
#define MT   4      // m-tiles per wave
#define XSTR 66     // x LDS row stride (uint pairs): 8B-aligned, 2-way banks (free)
#define NWAVE 4
#define ISL  16     // i-slice width per wave

// ---- workspace layout ----
#define W2H_BYTES 8388608            // 64*64*2*64*8 f16 = 8.4 MB
#define QS_OFF    W2H_BYTES
#define QS_BYTES  262144             // 64*64*32 f16
#define RB_OFF    (QS_OFF + QS_BYTES)
#define RB_BYTES  16384              // 64*64 f32
#define WS_NEED   (RB_OFF + RB_BYTES)

typedef float    floatx4 __attribute__((ext_vector_type(4)));
typedef _Float16 halfx8  __attribute__((ext_vector_type(8)));
typedef _Float16 halfx2  __attribute__((ext_vector_type(2)));

union H8 { halfx8 v8; halfx2 v2[4]; unsigned int u[4]; };

__device__ inline float leaky(float v) { return fmaxf(v, 0.01f * v); }

__device__ inline unsigned int pkrtz(float a, float b) {   // (a,b) -> f16x2, RTZ
    return __builtin_bit_cast(unsigned int, __builtin_amdgcn_cvt_pkrtz(a, b));
}

// ================= pre-kernel: W2->f16 fragments, q, rbias =================
// thread ranges: [0,524288) repack; [524288,655360) q; [655360,659456) rbias
__global__ __launch_bounds__(256)
void kan_pre(const float* __restrict__ W2, const float* __restrict__ W3,
             const float* __restrict__ b2, const float* __restrict__ lw,
             _Float16* __restrict__ w2h, _Float16* __restrict__ qs,
             float* __restrict__ rb)
{
    const int tid = blockIdx.x * 256 + threadIdx.x;
    if (tid < 524288) {
        // dest-linear: tid -> (o,i,f,lane); lane=(kh*16+col)
        const int lane = tid & 63, f = (tid >> 6) & 1, i = (tid >> 7) & 63, o = tid >> 13;
        const int col = lane & 15, kh = lane >> 4;
        const float* src = W2 + (((size_t)(o * 64 + i) * 32 + f * 16 + col) * 32 + kh * 8);
        float4 s0 = *(const float4*)src;
        float4 s1 = *(const float4*)(src + 4);
        uint4 p = { pkrtz(s0.x, s0.y), pkrtz(s0.z, s0.w),
                    pkrtz(s1.x, s1.y), pkrtz(s1.z, s1.w) };
        *(uint4*)(w2h + (size_t)tid * 8) = p;
    } else if (tid < 524288 + 131072) {
        const int qt = tid - 524288;
        const int h = qt & 31, oi = qt >> 5;
        const float* w2p = W2 + (size_t)oi * 1024 + h;
        const float* w3p = W3 + (size_t)oi * 32;
        float acc = 0.f;
        #pragma unroll 8
        for (int k = 0; k < 32; ++k) acc += w3p[k] * w2p[k * 32];
        qs[(size_t)oi * 32 + h] = (_Float16)(0.505f * lw[oi] * acc);
    } else if (tid < 524288 + 131072 + 4096) {
        const int oi = tid - 524288 - 131072;
        const float* w3p = W3 + (size_t)oi * 32;
        const float* b2p = b2 + (size_t)oi * 32;
        float acc = 0.f;
        #pragma unroll 8
        for (int k = 0; k < 32; ++k) acc += w3p[k] * b2p[k];
        rb[oi] = 0.505f * lw[oi] * acc;
    }
}

// ================= main kernel =================
__global__ __launch_bounds__(256, 4)
void kan_kernel(const float* __restrict__ x,  const float* __restrict__ W1,
                const float* __restrict__ b1, const float* __restrict__ W3,
                const float* __restrict__ b2, const float* __restrict__ b3,
                const float* __restrict__ lw, const float* __restrict__ bw,
                const _Float16* __restrict__ w2h, const _Float16* __restrict__ qsg,
                const float* __restrict__ rb, float* __restrict__ out)
{
    __shared__ unsigned int xsp[ROWS * XSTR];  // x dup-f16 pairs, 16.9 KB
    __shared__ _Float16 w1s[NI * H_];          // 4 KB
    __shared__ _Float16 b1s[NI * H_];          // 4 KB
    __shared__ unsigned int wbs[NI * H_];      // {.495*lw*w3, b2} f16 pairs, 8 KB
    __shared__ _Float16 qsl[NI * H_];          // q staged, 4 KB
    __shared__ float rcs[NWAVE][ROWS];         // per-seg row constants, 1 KB
    __shared__ float part[NWAVE][ROWS];        // per-wave i-slice partials, 1 KB

    const int t    = threadIdx.x;
    const int o    = blockIdx.x;               // o fastest -> same-o blocks share XCD
    const int row0 = blockIdx.y * ROWS;

    // ---- stage x tile as duplicated f16 pairs (256 thr x 16 floats) ----
    const float* xsrc = x + (size_t)row0 * NI;
    #pragma unroll
    for (int v = 0; v < 4; ++v) {
        int fe = (v * 256 + t) * 4;            // multiple of 4
        int r = fe >> 6, c = fe & 63;
        float4 xv = *(const float4*)(xsrc + fe);
        uint2 lo = { pkrtz(xv.x, xv.x), pkrtz(xv.y, xv.y) };
        uint2 hi = { pkrtz(xv.z, xv.z), pkrtz(xv.w, xv.w) };
        *(uint2*)(&xsp[r * XSTR + c])     = lo;   // 66r+c even -> 8B aligned
        *(uint2*)(&xsp[r * XSTR + c + 2]) = hi;
    }
    // ---- stage W1/b1 for this o as f16 (256 thr x 2 passes of 4) ----
    const float* w1g = W1 + (size_t)o * NI * H_;
    const float* b1g = b1 + (size_t)o * NI * H_;
    #pragma unroll
    for (int v = 0; v < 2; ++v) {
        int e = (v * 256 + t) * 4;
        float4 a = *(const float4*)(w1g + e);
        float4 c = *(const float4*)(b1g + e);
        uint2 pa = { pkrtz(a.x, a.y), pkrtz(a.z, a.w) };
        uint2 pc = { pkrtz(c.x, c.y), pkrtz(c.z, c.w) };
        *(uint2*)(w1s + e) = pa;
        *(uint2*)(b1s + e) = pc;
    }
    // ---- stage {nn=.495*lw*w3, b2} pairs: 2048 entries, 8 per thread ----
    {
        int e = t * 8;                          // i = e>>5, k = e&31 .. +7
        float l = 0.495f * lw[o * NI + (e >> 5)];
        const float* w3g = W3 + (size_t)o * NI * H_ + e;
        const float* b2g = b2 + (size_t)o * NI * H_ + e;
        float4 wa = *(const float4*)(w3g), wb = *(const float4*)(w3g + 4);
        float4 ba = *(const float4*)(b2g), bb = *(const float4*)(b2g + 4);
        uint4 p0 = { pkrtz(l * wa.x, ba.x), pkrtz(l * wa.y, ba.y),
                     pkrtz(l * wa.z, ba.z), pkrtz(l * wa.w, ba.w) };
        uint4 p1 = { pkrtz(l * wb.x, bb.x), pkrtz(l * wb.y, bb.y),
                     pkrtz(l * wb.z, bb.z), pkrtz(l * wb.w, bb.w) };
        *(uint4*)(&wbs[e])     = p0;
        *(uint4*)(&wbs[e + 4]) = p1;
    }
    // ---- stage q for this o (4 KB, 16B per thread) ----
    *(uint4*)(qsl + t * 8) = *(const uint4*)(qsg + (size_t)o * (NI * H_) + t * 8);
    __syncthreads();

    const int lane = t & 63, wave = t >> 6;
    const int col  = lane & 15;            // MFMA n-index (h2 k-slot) / A m-offset
    const int kh   = lane >> 4;            // contraction quad
    const int koff = kh * 8;
    const int i0   = wave * ISL;           // this wave's i-slice (16 wide)

    const halfx2 slope = { (_Float16)0.01f, (_Float16)0.01f };

    floatx4 pacc[MT];                      // |c| (negative-half) accumulators
    floatx4 acc1[MT];                      // q-MFMA (positive-half) accumulators
    #pragma unroll
    for (int m = 0; m < MT; ++m) {
        pacc[m] = floatx4{0.f, 0.f, 0.f, 0.f};
        acc1[m] = floatx4{0.f, 0.f, 0.f, 0.f};
    }

    // W2 f16 fragments: per (i,f): 64 lanes x 8 f16; addr = base + ii*1024 + f*512
    const _Float16* wbase = w2h + ((size_t)(o * NI + i0) * 2) * 512 + (size_t)lane * 8;
#define LDW(IIC, F) (*(const halfx8*)(wbase + (IIC) * 1024 + (F) * 512))

#define BODY(IIC, FA, FB) { \
    const int i = i0 + (IIC); \
    H8 w1v, b1v, qf; \
    w1v.v8 = *(const halfx8*)(w1s + i * H_ + koff); \
    b1v.v8 = *(const halfx8*)(b1s + i * H_ + koff); \
    qf.v8  = *(const halfx8*)(qsl + i * H_ + koff); \
    halfx2 qq0 = __builtin_bit_cast(halfx2, wbs[i * H_ + col]); \
    halfx2 qq1 = __builtin_bit_cast(halfx2, wbs[i * H_ + col + 16]); \
    float nn0 = (float)qq0[0], b2c0 = (float)qq0[1]; \
    float nn1 = (float)qq1[0], b2c1 = (float)qq1[1]; \
    _Pragma("unroll") \
    for (int m = 0; m < MT; ++m) { \
        halfx2 xx = __builtin_bit_cast(halfx2, xsp[(m * 16 + col) * XSTR + i]); \
        H8 af; \
        _Pragma("unroll") \
        for (int j = 0; j < 4; ++j) { \
            halfx2 h = __builtin_elementwise_fma(xx, w1v.v2[j], b1v.v2[j]); \
            af.v2[j] = __builtin_elementwise_max(h, h * slope); \
        } \
        floatx4 c0 = { b2c0, b2c0, b2c0, b2c0 }; \
        floatx4 c1 = { b2c1, b2c1, b2c1, b2c1 }; \
        c0 = __builtin_amdgcn_mfma_f32_16x16x32_f16(af.v8, (FA), c0, 0, 0, 0); \
        c1 = __builtin_amdgcn_mfma_f32_16x16x32_f16(af.v8, (FB), c1, 0, 0, 0); \
        acc1[m] = __builtin_amdgcn_mfma_f32_16x16x32_f16(af.v8, qf.v8, acc1[m], 0, 0, 0); \
        _Pragma("unroll") \
        for (int r = 0; r < 4; ++r) \
            pacc[m][r] = fmaf(nn0, fabsf(c0[r]), fmaf(nn1, fabsf(c1[r]), pacc[m][r])); \
    } \
}

    // 2-deep software pipeline over the 16 i's
    halfx8 f0a = LDW(0, 0), f0b = LDW(0, 1);
    halfx8 f1a = LDW(1, 0), f1b = LDW(1, 1);
    #pragma unroll
    for (int ii = 0; ii < 14; ii += 2) {
        halfx8 g0a = LDW(ii + 2, 0), g0b = LDW(ii + 2, 1);
        BODY(ii, f0a, f0b);
        halfx8 g1a = LDW(ii + 3, 0), g1b = LDW(ii + 3, 1);
        BODY(ii + 1, f1a, f1b);
        f0a = g0a; f0b = g0b; f1a = g1a; f1b = g1b;
    }
    BODY(14, f0a, f0b);
    BODY(15, f1a, f1b);
#undef BODY
#undef LDW

    // ---- in-wave reduce over the 16 col lanes, deposit i-slice partials ----
    // acc1 columns are identical (broadcast B) -> add once at col==0, no reduce.
    #pragma unroll
    for (int m = 0; m < MT; ++m) {
        #pragma unroll
        for (int r = 0; r < 4; ++r) {
            float v = pacc[m][r];
            v += __shfl_xor(v, 1, 64);
            v += __shfl_xor(v, 2, 64);
            v += __shfl_xor(v, 4, 64);
            v += __shfl_xor(v, 8, 64);
            if (col == 0)
                part[wave][m * 16 + kh * 4 + r] = v + acc1[m][r];  // C row = kh*4+r
        }
    }

    // ---- per-row constants, 4-way parallel over i-segments ----
    {
        const int row = t & 63, seg = t >> 6;
        float s = 0.f;
        const float* bwp = bw + o * NI;
        const float* lp  = lw + o * NI;
        const float* b3p = b3 + o * NI;
        const float* rbp = rb + o * NI;
        #pragma unroll
        for (int u = 0; u < NI / NWAVE; ++u) {
            int i = seg * (NI / NWAVE) + u;
            halfx2 hx = __builtin_bit_cast(halfx2, xsp[row * XSTR + i]);
            s += bwp[i] * leaky((float)hx[0]) + lp[i] * b3p[i] + rbp[i];
        }
        rcs[seg][row] = s;
    }
    __syncthreads();

    // ---- cross-wave sum + per-row constants, write out[b,o] ----
    if (t < ROWS) {
        float v = 0.f;
        #pragma unroll
        for (int w = 0; w < NWAVE; ++w) v += part[w][t] + rcs[w][t];
        out[(size_t)(row0 + t) * NO + o] = v;
    }
}

// ================= fallback (R16 verbatim, no workspace) =================
__global__ __launch_bounds__(256, 6)
void kan_fb(const float* __restrict__ x,  const float* __restrict__ W1,
            const float* __restrict__ b1, const float* __restrict__ W2,
            const float* __restrict__ b2, const float* __restrict__ W3,
            const float* __restrict__ b3, const float* __restrict__ lw,
            const float* __restrict__ bw, float* __restrict__ out)
{
    __shared__ unsigned int xsp[32 * XSTR];
    __shared__ _Float16 w1s[NI * H_];
    __shared__ _Float16 b1s[NI * H_];
    __shared__ unsigned int wbs[NI * H_];
    __shared__ float rcs[8][32];
    __shared__ float part[4][32];

    const int t    = threadIdx.x;
    const int o    = blockIdx.x;
    const int row0 = blockIdx.y * 32;

    const float* xsrc = x + (size_t)row0 * NI;
    #pragma unroll
    for (int v = 0; v < 2; ++v) {
        int fe = (v * 256 + t) * 4;
        int r = fe >> 6, c = fe & 63;
        float4 xv = *(const float4*)(xsrc + fe);
        uint2 lo = { pkrtz(xv.x, xv.x), pkrtz(xv.y, xv.y) };
        uint2 hi = { pkrtz(xv.z, xv.z), pkrtz(xv.w, xv.w) };
        *(uint2*)(&xsp[r * XSTR + c])     = lo;
        *(uint2*)(&xsp[r * XSTR + c + 2]) = hi;
    }
    const float* w1g = W1 + (size_t)o * NI * H_;
    const float* b1g = b1 + (size_t)o * NI * H_;
    #pragma unroll
    for (int v = 0; v < 2; ++v) {
        int e = (v * 256 + t) * 4;
        float4 a = *(const float4*)(w1g + e);
        float4 c = *(const float4*)(b1g + e);
        uint2 pa = { pkrtz(a.x, a.y), pkrtz(a.z, a.w) };
        uint2 pc = { pkrtz(c.x, c.y), pkrtz(c.z, c.w) };
        *(uint2*)(w1s + e) = pa;
        *(uint2*)(b1s + e) = pc;
    }
    {
        int e = t * 8;
        float l = lw[o * NI + (e >> 5)];
        const float* w3g = W3 + (size_t)o * NI * H_ + e;
        const float* b2g = b2 + (size_t)o * NI * H_ + e;
        float4 wa = *(const float4*)(w3g), wb = *(const float4*)(w3g + 4);
        float4 ba = *(const float4*)(b2g), bb = *(const float4*)(b2g + 4);
        uint4 p0 = { pkrtz(l * wa.x, ba.x), pkrtz(l * wa.y, ba.y),
                     pkrtz(l * wa.z, ba.z), pkrtz(l * wa.w, ba.w) };
        uint4 p1 = { pkrtz(l * wb.x, bb.x), pkrtz(l * wb.y, bb.y),
                     pkrtz(l * wb.z, bb.z), pkrtz(l * wb.w, bb.w) };
        *(uint4*)(&wbs[e])     = p0;
        *(uint4*)(&wbs[e + 4]) = p1;
    }
    __syncthreads();

    const int lane = t & 63, wave = t >> 6;
    const int col  = lane & 15;
    const int kh   = lane >> 4;
    const int koff = kh * 8;
    const int i0   = wave * 16;

    const float* w2p0 = W2 + ((size_t)(o * NI + i0) * H_ + col) * H_ + koff;
    const float* w2p1 = w2p0 + 16 * H_;
    const halfx2 slope = { (_Float16)0.01f, (_Float16)0.01f };

    floatx4 pacc[2];
    #pragma unroll
    for (int m = 0; m < 2; ++m) pacc[m] = floatx4{0.f, 0.f, 0.f, 0.f};

    floatx4 a0 = *(const floatx4*)(w2p0);
    floatx4 a1 = *(const floatx4*)(w2p0 + 4);
    floatx4 a2 = *(const floatx4*)(w2p1);
    floatx4 a3 = *(const floatx4*)(w2p1 + 4);

    #pragma unroll 2
    for (int ii = 0; ii < 16; ++ii) {
        const int i = i0 + ii;
        floatx4 n0, n1, n2, n3;
        if (ii < 15) {
            const float* np0 = w2p0 + (ii + 1) * (H_ * H_);
            const float* np1 = w2p1 + (ii + 1) * (H_ * H_);
            n0 = *(const floatx4*)(np0);
            n1 = *(const floatx4*)(np0 + 4);
            n2 = *(const floatx4*)(np1);
            n3 = *(const floatx4*)(np1 + 4);
        }
        H8 bf0, bf1;
        bf0.u[0] = pkrtz(a0[0], a0[1]);  bf0.u[1] = pkrtz(a0[2], a0[3]);
        bf0.u[2] = pkrtz(a1[0], a1[1]);  bf0.u[3] = pkrtz(a1[2], a1[3]);
        bf1.u[0] = pkrtz(a2[0], a2[1]);  bf1.u[1] = pkrtz(a2[2], a2[3]);
        bf1.u[2] = pkrtz(a3[0], a3[1]);  bf1.u[3] = pkrtz(a3[2], a3[3]);
        H8 w1v, b1v;
        w1v.v8 = *(const halfx8*)(w1s + i * H_ + koff);
        b1v.v8 = *(const halfx8*)(b1s + i * H_ + koff);
        halfx2 q0 = __builtin_bit_cast(halfx2, wbs[i * H_ + col]);
        halfx2 q1 = __builtin_bit_cast(halfx2, wbs[i * H_ + col + 16]);
        float w3e0 = (float)q0[0], b2c0 = (float)q0[1];
        float w3e1 = (float)q1[0], b2c1 = (float)q1[1];
        float p0 = 0.505f * w3e0, nn0 = 0.495f * w3e0;
        float p1 = 0.505f * w3e1, nn1 = 0.495f * w3e1;
        #pragma unroll
        for (int m = 0; m < 2; ++m) {
            halfx2 xx = __builtin_bit_cast(halfx2, xsp[(m * 16 + col) * XSTR + i]);
            H8 af;
            #pragma unroll
            for (int j = 0; j < 4; ++j) {
                halfx2 h = __builtin_elementwise_fma(xx, w1v.v2[j], b1v.v2[j]);
                af.v2[j] = __builtin_elementwise_max(h, h * slope);
            }
            floatx4 c0 = { b2c0, b2c0, b2c0, b2c0 };
            floatx4 c1 = { b2c1, b2c1, b2c1, b2c1 };
            c0 = __builtin_amdgcn_mfma_f32_16x16x32_f16(af.v8, bf0.v8, c0, 0, 0, 0);
            c1 = __builtin_amdgcn_mfma_f32_16x16x32_f16(af.v8, bf1.v8, c1, 0, 0, 0);
            #pragma unroll
            for (int r = 0; r < 4; ++r) {
                float acc = pacc[m][r];
                acc = fmaf(p0,  c0[r],
                      fmaf(nn0, fabsf(c0[r]),
                      fmaf(p1,  c1[r],
                      fmaf(nn1, fabsf(c1[r]), acc))));
                pacc[m][r] = acc;
            }
        }
        a0 = n0; a1 = n1; a2 = n2; a3 = n3;
    }
    #pragma unroll
    for (int m = 0; m < 2; ++m) {
        #pragma unroll
        for (int r = 0; r < 4; ++r) {
            float v = pacc[m][r];
            v += __shfl_xor(v, 1, 64);
            v += __shfl_xor(v, 2, 64);
            v += __shfl_xor(v, 4, 64);
            v += __shfl_xor(v, 8, 64);
            if (col == 0)
                part[wave][m * 16 + kh * 4 + r] = v;
        }
    }
    {
        const int row = t & 31, seg = t >> 5;
        float s = 0.f;
        const float* bwp = bw + o * NI;
        const float* lp  = lw + o * NI;
        const float* b3p = b3 + o * NI;
        #pragma unroll
        for (int u = 0; u < 8; ++u) {
            int i = seg * 8 + u;
            halfx2 hx = __builtin_bit_cast(halfx2, xsp[row * XSTR + i]);
            s += bwp[i] * leaky((float)hx[0]) + lp[i] * b3p[i];
        }
        rcs[seg][row] = s;
    }
    __syncthreads();
    if (t < 32) {
        float v = 0.f;
        #pragma unroll
        for (int w = 0; w < 4; ++w) v += part[w][t];
        #pragma unroll
        for (int s = 0; s < 8; ++s) v += rcs[s][t];
        out[(size_t)(row0 + t) * NO + o] = v;
    }
}

extern "C" void kernel_launch(void* const* d_in, const int* in_sizes, int n_in,
                              void* d_out, int out_size, void* d_ws, size_t ws_size,
                              hipStream_t stream) {
    const float* x  = (const float*)d_in[0];
    const float* W1 = (const float*)d_in[1];
    const float* b1 = (const float*)d_in[2];
    const float* W2 = (const float*)d_in[3];
    const float* b2 = (const float*)d_in[4];
    const float* W3 = (const float*)d_in[5];
    const float* b3 = (const float*)d_in[6];
    const float* lw = (const float*)d_in[7];
    const float* bw = (const float*)d_in[8];
    float* out = (float*)d_out;

    if (d_ws && ws_size >= (size_t)WS_NEED) {
        _Float16* w2h = (_Float16*)d_ws;
        _Float16* qsg = (_Float16*)((char*)d_ws + QS_OFF);
        float*    rb  = (float*)((char*)d_ws + RB_OFF);
        kan_pre<<<dim3(2576), dim3(256), 0, stream>>>(W2, W3, b2, lw, w2h, qsg, rb);
        dim3 grid(NO, NB / ROWS);   // 1024 blocks, o fastest (XCD-local), 4/CU
        kan_kernel<<<grid, dim3(256), 0, stream>>>(x, W1, b1, W3, b2, b3, lw, bw,
                                                   w2h, qsg, rb, out);
    } else {
        dim3 grid(NO, NB / 32);     // fallback: R16 config
        kan_fb<<<grid, dim3(256), 0, stream>>>(x, W1, b1, W2, b2, W3, b3, lw, bw, out);
    }
}

// Round 6
// 111.041 us; speedup vs baseline: 4.3062x; 4.3062x over previous
//
#include <hip/hip_runtime.h>

// KANLayer: B=1024, I=64, O=64, H=32. ALL I/O float32 (per reference).
// out[b,o] = sum_i [ bw[o,i]*leaky(x[b,i]) + lw[o,i]*( sum_k W3[o,i,k]*h2[k] + b3[o,i] ) ]
//   h1[h] = leaky(x[b,i]*W1[o,i,h] + b1[o,i,h])
//   h2[k] = leaky(sum_h h1[h]*W2[o,i,k,h] + b2[o,i,k])
//
// R18 = R17's validated math in R13's validated loop shape.
// R17 post-mortem: math passed (q/rbias/acc1 folding correct) but the
// fully-unrolled 16-body pipeline spilled (WRITE 492MB scratch, 394us).
// Pattern (3x confirmed): any deviation from R13's loop shape spills;
// R13's shape (one-deep if(ii<15) prefetch, unroll 2, 256thr) never has.
// R18 main loop = R13 skeleton exactly, with:
//   - W2 loaded as pre-repacked f16 fragments (kills 16 pkrtz/ii, halves
//     prefetch regs f32->f16)
//   - acc1 MFMA (B=broadcast q) replaces the positive leaky half:
//     epilogue 16 FMA/m -> 8 FMA/m (only .495*lw*w3*|c| terms)
//   - leaky(v)*w = (.505w)*v + (.495w)*|v|;  sum_k(.505w_k)c[r,k] =
//     sum_h h1[r,h]*q[h] (+rbias, added in rc loop); c includes b2 via C-in.
// Per-ii VALU 112 -> ~70. VGPR est ~75 (52 - 8 + 16 + 4) < cap 128.
// kan_pre identical to R17 (validated): W2->f16 frag order, q, rbias.
// Verify order: WRITE_SIZE(main) ~2MB + VGPR 70-85 (no spill), then
// dispatch main 28-33us + pre 6-9us, VALUBusy 45-55%.

#define H_   32
#define NI   64
#define NO   64
#define NB   1024
#define ROWS 64     // batch rows per block (4 m-tiles)
#define MT   4      // m-tiles per wave
#define XSTR 66     // x LDS row stride (uint pairs): 8B-aligned, 2-way banks (free)
#define NWAVE 4
#define ISL  16     // i-slice width per wave

// ---- workspace layout ----
#define W2H_BYTES 8388608            // 64*64*2*64*8 f16 = 8.4 MB
#define QS_OFF    W2H_BYTES
#define QS_BYTES  262144             // 64*64*32 f16
#define RB_OFF    (QS_OFF + QS_BYTES)
#define RB_BYTES  16384              // 64*64 f32
#define WS_NEED   (RB_OFF + RB_BYTES)

typedef float    floatx4 __attribute__((ext_vector_type(4)));
typedef _Float16 halfx8  __attribute__((ext_vector_type(8)));
typedef _Float16 halfx2  __attribute__((ext_vector_type(2)));

union H8 { halfx8 v8; halfx2 v2[4]; unsigned int u[4]; };

__device__ inline float leaky(float v) { return fmaxf(v, 0.01f * v); }

__device__ inline unsigned int pkrtz(float a, float b) {   // (a,b) -> f16x2, RTZ
    return __builtin_bit_cast(unsigned int, __builtin_amdgcn_cvt_pkrtz(a, b));
}

// ================= pre-kernel: W2->f16 fragments, q, rbias =================
// thread ranges: [0,524288) repack; [524288,655360) q; [655360,659456) rbias
__global__ __launch_bounds__(256)
void kan_pre(const float* __restrict__ W2, const float* __restrict__ W3,
             const float* __restrict__ b2, const float* __restrict__ lw,
             _Float16* __restrict__ w2h, _Float16* __restrict__ qs,
             float* __restrict__ rb)
{
    const int tid = blockIdx.x * 256 + threadIdx.x;
    if (tid < 524288) {
        // dest-linear: tid -> (o,i,f,lane); lane=(kh*16+col)
        const int lane = tid & 63, f = (tid >> 6) & 1, i = (tid >> 7) & 63, o = tid >> 13;
        const int col = lane & 15, kh = lane >> 4;
        const float* src = W2 + (((size_t)(o * 64 + i) * 32 + f * 16 + col) * 32 + kh * 8);
        float4 s0 = *(const float4*)src;
        float4 s1 = *(const float4*)(src + 4);
        uint4 p = { pkrtz(s0.x, s0.y), pkrtz(s0.z, s0.w),
                    pkrtz(s1.x, s1.y), pkrtz(s1.z, s1.w) };
        *(uint4*)(w2h + (size_t)tid * 8) = p;
    } else if (tid < 524288 + 131072) {
        const int qt = tid - 524288;
        const int h = qt & 31, oi = qt >> 5;
        const float* w2p = W2 + (size_t)oi * 1024 + h;
        const float* w3p = W3 + (size_t)oi * 32;
        float acc = 0.f;
        #pragma unroll 8
        for (int k = 0; k < 32; ++k) acc += w3p[k] * w2p[k * 32];
        qs[(size_t)oi * 32 + h] = (_Float16)(0.505f * lw[oi] * acc);
    } else if (tid < 524288 + 131072 + 4096) {
        const int oi = tid - 524288 - 131072;
        const float* w3p = W3 + (size_t)oi * 32;
        const float* b2p = b2 + (size_t)oi * 32;
        float acc = 0.f;
        #pragma unroll 8
        for (int k = 0; k < 32; ++k) acc += w3p[k] * b2p[k];
        rb[oi] = 0.505f * lw[oi] * acc;
    }
}

// ================= main kernel (R13 loop shape + R17 math) =================
__global__ __launch_bounds__(256, 4)
void kan_kernel(const float* __restrict__ x,  const float* __restrict__ W1,
                const float* __restrict__ b1, const float* __restrict__ W3,
                const float* __restrict__ b2, const float* __restrict__ b3,
                const float* __restrict__ lw, const float* __restrict__ bw,
                const _Float16* __restrict__ w2h, const _Float16* __restrict__ qsg,
                const float* __restrict__ rb, float* __restrict__ out)
{
    __shared__ unsigned int xsp[ROWS * XSTR];  // x dup-f16 pairs, 16.9 KB
    __shared__ _Float16 w1s[NI * H_];          // 4 KB
    __shared__ _Float16 b1s[NI * H_];          // 4 KB
    __shared__ unsigned int wbs[NI * H_];      // {.495*lw*w3, b2} f16 pairs, 8 KB
    __shared__ _Float16 qsl[NI * H_];          // q staged, 4 KB
    __shared__ float rcs[NWAVE][ROWS];         // per-seg row constants, 1 KB
    __shared__ float part[NWAVE][ROWS];        // per-wave i-slice partials, 1 KB

    const int t    = threadIdx.x;
    const int o    = blockIdx.x;               // o fastest -> same-o blocks share XCD
    const int row0 = blockIdx.y * ROWS;

    // ---- stage x tile as duplicated f16 pairs (256 thr x 16 floats) ----
    const float* xsrc = x + (size_t)row0 * NI;
    #pragma unroll
    for (int v = 0; v < 4; ++v) {
        int fe = (v * 256 + t) * 4;            // multiple of 4
        int r = fe >> 6, c = fe & 63;
        float4 xv = *(const float4*)(xsrc + fe);
        uint2 lo = { pkrtz(xv.x, xv.x), pkrtz(xv.y, xv.y) };
        uint2 hi = { pkrtz(xv.z, xv.z), pkrtz(xv.w, xv.w) };
        *(uint2*)(&xsp[r * XSTR + c])     = lo;   // 66r+c even -> 8B aligned
        *(uint2*)(&xsp[r * XSTR + c + 2]) = hi;
    }
    // ---- stage W1/b1 for this o as f16 (256 thr x 2 passes of 4) ----
    const float* w1g = W1 + (size_t)o * NI * H_;
    const float* b1g = b1 + (size_t)o * NI * H_;
    #pragma unroll
    for (int v = 0; v < 2; ++v) {
        int e = (v * 256 + t) * 4;
        float4 a = *(const float4*)(w1g + e);
        float4 c = *(const float4*)(b1g + e);
        uint2 pa = { pkrtz(a.x, a.y), pkrtz(a.z, a.w) };
        uint2 pc = { pkrtz(c.x, c.y), pkrtz(c.z, c.w) };
        *(uint2*)(w1s + e) = pa;
        *(uint2*)(b1s + e) = pc;
    }
    // ---- stage {nn=.495*lw*w3, b2} pairs: 2048 entries, 8 per thread ----
    {
        int e = t * 8;                          // i = e>>5, k = e&31 .. +7
        float l = 0.495f * lw[o * NI + (e >> 5)];
        const float* w3g = W3 + (size_t)o * NI * H_ + e;
        const float* b2g = b2 + (size_t)o * NI * H_ + e;
        float4 wa = *(const float4*)(w3g), wb = *(const float4*)(w3g + 4);
        float4 ba = *(const float4*)(b2g), bb = *(const float4*)(b2g + 4);
        uint4 p0 = { pkrtz(l * wa.x, ba.x), pkrtz(l * wa.y, ba.y),
                     pkrtz(l * wa.z, ba.z), pkrtz(l * wa.w, ba.w) };
        uint4 p1 = { pkrtz(l * wb.x, bb.x), pkrtz(l * wb.y, bb.y),
                     pkrtz(l * wb.z, bb.z), pkrtz(l * wb.w, bb.w) };
        *(uint4*)(&wbs[e])     = p0;
        *(uint4*)(&wbs[e + 4]) = p1;
    }
    // ---- stage q for this o (4 KB, 16B per thread) ----
    *(uint4*)(qsl + t * 8) = *(const uint4*)(qsg + (size_t)o * (NI * H_) + t * 8);
    __syncthreads();

    const int lane = t & 63, wave = t >> 6;
    const int col  = lane & 15;            // MFMA n-index (h2 k-slot) / A m-offset
    const int kh   = lane >> 4;            // contraction quad
    const int koff = kh * 8;
    const int i0   = wave * ISL;           // this wave's i-slice (16 wide)

    const halfx2 slope = { (_Float16)0.01f, (_Float16)0.01f };

    floatx4 pacc[MT];                      // |c| (negative-half) accumulators
    floatx4 acc1[MT];                      // q-MFMA (positive-half) accumulators
    #pragma unroll
    for (int m = 0; m < MT; ++m) {
        pacc[m] = floatx4{0.f, 0.f, 0.f, 0.f};
        acc1[m] = floatx4{0.f, 0.f, 0.f, 0.f};
    }

    // W2 f16 fragments: per (i,f): 64 lanes x 8 f16; elem = (o*NI+i)*1024 + f*512 + lane*8
    const _Float16* wbase = w2h + (size_t)(o * NI + i0) * 1024 + (size_t)lane * 8;

    // prime the prefetch registers with iter 0's W2 fragments (R13 shape)
    halfx8 cA = *(const halfx8*)(wbase);
    halfx8 cB = *(const halfx8*)(wbase + 512);

    #pragma unroll 2
    for (int ii = 0; ii < ISL; ++ii) {
        const int i = i0 + ii;

        // issue next iteration's W2 loads before consuming this one's
        halfx8 nA, nB;
        if (ii < ISL - 1) {
            const _Float16* np = wbase + (ii + 1) * 1024;
            nA = *(const halfx8*)(np);
            nB = *(const halfx8*)(np + 512);
        }

        H8 w1v, b1v, qf;
        w1v.v8 = *(const halfx8*)(w1s + i * H_ + koff);
        b1v.v8 = *(const halfx8*)(b1s + i * H_ + koff);
        qf.v8  = *(const halfx8*)(qsl + i * H_ + koff);

        // per-k constants from LDS: {.495*lw*w3, b2} f16 pairs (broadcast reads)
        halfx2 q0 = __builtin_bit_cast(halfx2, wbs[i * H_ + col]);
        halfx2 q1 = __builtin_bit_cast(halfx2, wbs[i * H_ + col + 16]);
        float nn0 = (float)q0[0], b2c0 = (float)q0[1];
        float nn1 = (float)q1[0], b2c1 = (float)q1[1];

        #pragma unroll
        for (int m = 0; m < MT; ++m) {
            halfx2 xx = __builtin_bit_cast(halfx2, xsp[(m * 16 + col) * XSTR + i]);
            H8 af;
            #pragma unroll
            for (int j = 0; j < 4; ++j) {
                halfx2 h = __builtin_elementwise_fma(xx, w1v.v2[j], b1v.v2[j]);
                af.v2[j] = __builtin_elementwise_max(h, h * slope);  // pk leaky
            }
            floatx4 c0 = { b2c0, b2c0, b2c0, b2c0 };   // b2 folded into C
            floatx4 c1 = { b2c1, b2c1, b2c1, b2c1 };
            c0 = __builtin_amdgcn_mfma_f32_16x16x32_f16(af.v8, cA, c0, 0, 0, 0);
            c1 = __builtin_amdgcn_mfma_f32_16x16x32_f16(af.v8, cB, c1, 0, 0, 0);
            acc1[m] = __builtin_amdgcn_mfma_f32_16x16x32_f16(af.v8, qf.v8, acc1[m], 0, 0, 0);
            // negative-half epilogue only: pacc += (.495*lw*w3)*|c|
            #pragma unroll
            for (int r = 0; r < 4; ++r)
                pacc[m][r] = fmaf(nn0, fabsf(c0[r]),
                             fmaf(nn1, fabsf(c1[r]), pacc[m][r]));
        }

        cA = nA; cB = nB;
    }

    // ---- in-wave reduce over the 16 col lanes, deposit i-slice partials ----
    // acc1 columns are identical (broadcast B) -> add once at col==0, no reduce.
    #pragma unroll
    for (int m = 0; m < MT; ++m) {
        #pragma unroll
        for (int r = 0; r < 4; ++r) {
            float v = pacc[m][r];
            v += __shfl_xor(v, 1, 64);
            v += __shfl_xor(v, 2, 64);
            v += __shfl_xor(v, 4, 64);
            v += __shfl_xor(v, 8, 64);
            if (col == 0)
                part[wave][m * 16 + kh * 4 + r] = v + acc1[m][r];  // C row = kh*4+r
        }
    }

    // ---- per-row constants, 4-way parallel over i-segments ----
    {
        const int row = t & 63, seg = t >> 6;
        float s = 0.f;
        const float* bwp = bw + o * NI;
        const float* lp  = lw + o * NI;
        const float* b3p = b3 + o * NI;
        const float* rbp = rb + o * NI;
        #pragma unroll
        for (int u = 0; u < NI / NWAVE; ++u) {
            int i = seg * (NI / NWAVE) + u;
            halfx2 hx = __builtin_bit_cast(halfx2, xsp[row * XSTR + i]);
            s += bwp[i] * leaky((float)hx[0]) + lp[i] * b3p[i] + rbp[i];
        }
        rcs[seg][row] = s;
    }
    __syncthreads();

    // ---- cross-wave sum + per-row constants, write out[b,o] ----
    if (t < ROWS) {
        float v = 0.f;
        #pragma unroll
        for (int w = 0; w < NWAVE; ++w) v += part[w][t] + rcs[w][t];
        out[(size_t)(row0 + t) * NO + o] = v;
    }
}

// ================= fallback (R16 verbatim, no workspace) =================
__global__ __launch_bounds__(256, 6)
void kan_fb(const float* __restrict__ x,  const float* __restrict__ W1,
            const float* __restrict__ b1, const float* __restrict__ W2,
            const float* __restrict__ b2, const float* __restrict__ W3,
            const float* __restrict__ b3, const float* __restrict__ lw,
            const float* __restrict__ bw, float* __restrict__ out)
{
    __shared__ unsigned int xsp[32 * XSTR];
    __shared__ _Float16 w1s[NI * H_];
    __shared__ _Float16 b1s[NI * H_];
    __shared__ unsigned int wbs[NI * H_];
    __shared__ float rcs[8][32];
    __shared__ float part[4][32];

    const int t    = threadIdx.x;
    const int o    = blockIdx.x;
    const int row0 = blockIdx.y * 32;

    const float* xsrc = x + (size_t)row0 * NI;
    #pragma unroll
    for (int v = 0; v < 2; ++v) {
        int fe = (v * 256 + t) * 4;
        int r = fe >> 6, c = fe & 63;
        float4 xv = *(const float4*)(xsrc + fe);
        uint2 lo = { pkrtz(xv.x, xv.x), pkrtz(xv.y, xv.y) };
        uint2 hi = { pkrtz(xv.z, xv.z), pkrtz(xv.w, xv.w) };
        *(uint2*)(&xsp[r * XSTR + c])     = lo;
        *(uint2*)(&xsp[r * XSTR + c + 2]) = hi;
    }
    const float* w1g = W1 + (size_t)o * NI * H_;
    const float* b1g = b1 + (size_t)o * NI * H_;
    #pragma unroll
    for (int v = 0; v < 2; ++v) {
        int e = (v * 256 + t) * 4;
        float4 a = *(const float4*)(w1g + e);
        float4 c = *(const float4*)(b1g + e);
        uint2 pa = { pkrtz(a.x, a.y), pkrtz(a.z, a.w) };
        uint2 pc = { pkrtz(c.x, c.y), pkrtz(c.z, c.w) };
        *(uint2*)(w1s + e) = pa;
        *(uint2*)(b1s + e) = pc;
    }
    {
        int e = t * 8;
        float l = lw[o * NI + (e >> 5)];
        const float* w3g = W3 + (size_t)o * NI * H_ + e;
        const float* b2g = b2 + (size_t)o * NI * H_ + e;
        float4 wa = *(const float4*)(w3g), wb = *(const float4*)(w3g + 4);
        float4 ba = *(const float4*)(b2g), bb = *(const float4*)(b2g + 4);
        uint4 p0 = { pkrtz(l * wa.x, ba.x), pkrtz(l * wa.y, ba.y),
                     pkrtz(l * wa.z, ba.z), pkrtz(l * wa.w, ba.w) };
        uint4 p1 = { pkrtz(l * wb.x, bb.x), pkrtz(l * wb.y, bb.y),
                     pkrtz(l * wb.z, bb.z), pkrtz(l * wb.w, bb.w) };
        *(uint4*)(&wbs[e])     = p0;
        *(uint4*)(&wbs[e + 4]) = p1;
    }
    __syncthreads();

    const int lane = t & 63, wave = t >> 6;
    const int col  = lane & 15;
    const int kh   = lane >> 4;
    const int koff = kh * 8;
    const int i0   = wave * 16;

    const float* w2p0 = W2 + ((size_t)(o * NI + i0) * H_ + col) * H_ + koff;
    const float* w2p1 = w2p0 + 16 * H_;
    const halfx2 slope = { (_Float16)0.01f, (_Float16)0.01f };

    floatx4 pacc[2];
    #pragma unroll
    for (int m = 0; m < 2; ++m) pacc[m] = floatx4{0.f, 0.f, 0.f, 0.f};

    floatx4 a0 = *(const floatx4*)(w2p0);
    floatx4 a1 = *(const floatx4*)(w2p0 + 4);
    floatx4 a2 = *(const floatx4*)(w2p1);
    floatx4 a3 = *(const floatx4*)(w2p1 + 4);

    #pragma unroll 2
    for (int ii = 0; ii < 16; ++ii) {
        const int i = i0 + ii;
        floatx4 n0, n1, n2, n3;
        if (ii < 15) {
            const float* np0 = w2p0 + (ii + 1) * (H_ * H_);
            const float* np1 = w2p1 + (ii + 1) * (H_ * H_);
            n0 = *(const floatx4*)(np0);
            n1 = *(const floatx4*)(np0 + 4);
            n2 = *(const floatx4*)(np1);
            n3 = *(const floatx4*)(np1 + 4);
        }
        H8 bf0, bf1;
        bf0.u[0] = pkrtz(a0[0], a0[1]);  bf0.u[1] = pkrtz(a0[2], a0[3]);
        bf0.u[2] = pkrtz(a1[0], a1[1]);  bf0.u[3] = pkrtz(a1[2], a1[3]);
        bf1.u[0] = pkrtz(a2[0], a2[1]);  bf1.u[1] = pkrtz(a2[2], a2[3]);
        bf1.u[2] = pkrtz(a3[0], a3[1]);  bf1.u[3] = pkrtz(a3[2], a3[3]);
        H8 w1v, b1v;
        w1v.v8 = *(const halfx8*)(w1s + i * H_ + koff);
        b1v.v8 = *(const halfx8*)(b1s + i * H_ + koff);
        halfx2 q0 = __builtin_bit_cast(halfx2, wbs[i * H_ + col]);
        halfx2 q1 = __builtin_bit_cast(halfx2, wbs[i * H_ + col + 16]);
        float w3e0 = (float)q0[0], b2c0 = (float)q0[1];
        float w3e1 = (float)q1[0], b2c1 = (float)q1[1];
        float p0 = 0.505f * w3e0, nn0 = 0.495f * w3e0;
        float p1 = 0.505f * w3e1, nn1 = 0.495f * w3e1;
        #pragma unroll
        for (int m = 0; m < 2; ++m) {
            halfx2 xx = __builtin_bit_cast(halfx2, xsp[(m * 16 + col) * XSTR + i]);
            H8 af;
            #pragma unroll
            for (int j = 0; j < 4; ++j) {
                halfx2 h = __builtin_elementwise_fma(xx, w1v.v2[j], b1v.v2[j]);
                af.v2[j] = __builtin_elementwise_max(h, h * slope);
            }
            floatx4 c0 = { b2c0, b2c0, b2c0, b2c0 };
            floatx4 c1 = { b2c1, b2c1, b2c1, b2c1 };
            c0 = __builtin_amdgcn_mfma_f32_16x16x32_f16(af.v8, bf0.v8, c0, 0, 0, 0);
            c1 = __builtin_amdgcn_mfma_f32_16x16x32_f16(af.v8, bf1.v8, c1, 0, 0, 0);
            #pragma unroll
            for (int r = 0; r < 4; ++r) {
                float acc = pacc[m][r];
                acc = fmaf(p0,  c0[r],
                      fmaf(nn0, fabsf(c0[r]),
                      fmaf(p1,  c1[r],
                      fmaf(nn1, fabsf(c1[r]), acc))));
                pacc[m][r] = acc;
            }
        }
        a0 = n0; a1 = n1; a2 = n2; a3 = n3;
    }
    #pragma unroll
    for (int m = 0; m < 2; ++m) {
        #pragma unroll
        for (int r = 0; r < 4; ++r) {
            float v = pacc[m][r];
            v += __shfl_xor(v, 1, 64);
            v += __shfl_xor(v, 2, 64);
            v += __shfl_xor(v, 4, 64);
            v += __shfl_xor(v, 8, 64);
            if (col == 0)
                part[wave][m * 16 + kh * 4 + r] = v;
        }
    }
    {
        const int row = t & 31, seg = t >> 5;
        float s = 0.f;
        const float* bwp = bw + o * NI;
        const float* lp  = lw + o * NI;
        const float* b3p = b3 + o * NI;
        #pragma unroll
        for (int u = 0; u < 8; ++u) {
            int i = seg * 8 + u;
            halfx2 hx = __builtin_bit_cast(halfx2, xsp[row * XSTR + i]);
            s += bwp[i] * leaky((float)hx[0]) + lp[i] * b3p[i];
        }
        rcs[seg][row] = s;
    }
    __syncthreads();
    if (t < 32) {
        float v = 0.f;
        #pragma unroll
        for (int w = 0; w < 4; ++w) v += part[w][t];
        #pragma unroll
        for (int s = 0; s < 8; ++s) v += rcs[s][t];
        out[(size_t)(row0 + t) * NO + o] = v;
    }
}

extern "C" void kernel_launch(void* const* d_in, const int* in_sizes, int n_in,
                              void* d_out, int out_size, void* d_ws, size_t ws_size,
                              hipStream_t stream) {
    const float* x  = (const float*)d_in[0];
    const float* W1 = (const float*)d_in[1];
    const float* b1 = (const float*)d_in[2];
    const float* W2 = (const float*)d_in[3];
    const float* b2 = (const float*)d_in[4];
    const float* W3 = (const float*)d_in[5];
    const float* b3 = (const float*)d_in[6];
    const float* lw = (const float*)d_in[7];
    const float* bw = (const float*)d_in[8];
    float* out = (float*)d_out;

    if (d_ws && ws_size >= (size_t)WS_NEED) {
        _Float16* w2h = (_Float16*)d_ws;
        _Float16* qsg = (_Float16*)((char*)d_ws + QS_OFF);
        float*    rb  = (float*)((char*)d_ws + RB_OFF);
        kan_pre<<<dim3(2576), dim3(256), 0, stream>>>(W2, W3, b2, lw, w2h, qsg, rb);
        dim3 grid(NO, NB / ROWS);   // 1024 blocks, o fastest (XCD-local), 4/CU
        kan_kernel<<<grid, dim3(256), 0, stream>>>(x, W1, b1, W3, b2, b3, lw, bw,
                                                   w2h, qsg, rb, out);
    } else {
        dim3 grid(NO, NB / 32);     // fallback: R16 config
        kan_fb<<<grid, dim3(256), 0, stream>>>(x, W1, b1, W2, b2, W3, b3, lw, bw, out);
    }
}

// Round 7
// 110.218 us; speedup vs baseline: 4.3384x; 1.0075x over previous
//
#include <hip/hip_runtime.h>

// KANLayer: B=1024, I=64, O=64, H=32. ALL I/O float32 (per reference).
// out[b,o] = sum_i [ bw[o,i]*leaky(x[b,i]) + lw[o,i]*( sum_k W3[o,i,k]*h2[k] + b3[o,i] ) ]
//   h1[h] = leaky(x[b,i]*W1[o,i,h] + b1[o,i,h])
//   h2[k] = leaky(sum_h h1[h]*W2[o,i,k,h] + b2[o,i,k])
//
// R19 = R18 (111.0us, matched prediction: main ~31us inferred) + staging
// precompute. R18 confirmed instruction-count ~ time (main 43->~31 as VALU
// 112->70/ii). Remaining per-block staging does ~100 VALU of f32->f16
// conversion REPEATED by all 16 same-o blocks. R19 moves every conversion
// into kan_pre: x->dup-f16 pairs (xd), W1/b1->f16 (w1h/b1h), wbs pairs
// {.495*lw*w3, b2} (wbp). Main staging = ~9 uint4 copies, zero pkrtz.
// Loop body = R18 verbatim (never-spill shape, 4x confirmed):
//   - W2 pre-repacked f16 fragments, one-deep if(ii<15) prefetch, unroll 2
//   - acc1 MFMA (B=broadcast q) for the .505 leaky half; epilogue only
//     .495*lw*w3*|c| (8 fma/m); b2 folded into MFMA C-in.
// Verify order: kan_kernel back in top-5 at 26-29us, VGPR ~60,
// WRITE_SIZE(main) ~2MB; pre 8-9us; total ~105-107.

#define H_   32
#define NI   64
#define NO   64
#define NB   1024
#define ROWS 64     // batch rows per block (4 m-tiles)
#define MT   4      // m-tiles per wave
#define XSTR 66     // x LDS row stride (uint pairs): 8B-aligned, 2-way banks (free)
#define NWAVE 4
#define ISL  16     // i-slice width per wave

// ---- workspace layout (bytes) ----
#define W2H_OFF 0
#define W2H_BYTES 8388608            // 64*64*1024 f16 frags = 8.4 MB
#define QS_OFF   8388608
#define QS_BYTES 262144              // 64*64*32 f16
#define RB_OFF   8650752
#define RB_BYTES 16384               // 64*64 f32
#define XD_OFF   8667136
#define XD_BYTES 262144              // 1024*64 dup-f16 pairs (u32)
#define W1H_OFF  8929280
#define W1H_BYTES 262144             // 64*64*32 f16
#define B1H_OFF  9191424
#define B1H_BYTES 262144
#define WBP_OFF  9453568
#define WBP_BYTES 524288             // 64*64*32 u32 pairs
#define WS_NEED  9977856

typedef float    floatx4 __attribute__((ext_vector_type(4)));
typedef _Float16 halfx8  __attribute__((ext_vector_type(8)));
typedef _Float16 halfx2  __attribute__((ext_vector_type(2)));

union H8 { halfx8 v8; halfx2 v2[4]; unsigned int u[4]; };

__device__ inline float leaky(float v) { return fmaxf(v, 0.01f * v); }

__device__ inline unsigned int pkrtz(float a, float b) {   // (a,b) -> f16x2, RTZ
    return __builtin_bit_cast(unsigned int, __builtin_amdgcn_cvt_pkrtz(a, b));
}

// ================= pre-kernel =================
// ranges: [0,524288) W2 repack; +131072 q; +4096 rb; +16384 xd; +16384 w1h;
//         +16384 b1h; +16384 wbp.  total 724992 thr = 2832 blocks.
__global__ __launch_bounds__(256)
void kan_pre(const float* __restrict__ x,  const float* __restrict__ W1,
             const float* __restrict__ b1, const float* __restrict__ W2,
             const float* __restrict__ b2, const float* __restrict__ W3,
             const float* __restrict__ lw,
             _Float16* __restrict__ w2h, _Float16* __restrict__ qs,
             float* __restrict__ rb, unsigned int* __restrict__ xd,
             _Float16* __restrict__ w1h, _Float16* __restrict__ b1h,
             unsigned int* __restrict__ wbp)
{
    const int tid = blockIdx.x * 256 + threadIdx.x;
    if (tid < 524288) {
        // W2 -> f16 MFMA fragments, dest-linear: tid -> (o,i,f,lane)
        const int lane = tid & 63, f = (tid >> 6) & 1, i = (tid >> 7) & 63, o = tid >> 13;
        const int col = lane & 15, kh = lane >> 4;
        const float* src = W2 + (((size_t)(o * 64 + i) * 32 + f * 16 + col) * 32 + kh * 8);
        float4 s0 = *(const float4*)src;
        float4 s1 = *(const float4*)(src + 4);
        uint4 p = { pkrtz(s0.x, s0.y), pkrtz(s0.z, s0.w),
                    pkrtz(s1.x, s1.y), pkrtz(s1.z, s1.w) };
        *(uint4*)(w2h + (size_t)tid * 8) = p;
    } else if (tid < 655360) {
        // q[oi,h] = .505*lw*sum_k w3_k*W2[k,h]
        const int qt = tid - 524288;
        const int h = qt & 31, oi = qt >> 5;
        const float* w2p = W2 + (size_t)oi * 1024 + h;
        const float* w3p = W3 + (size_t)oi * 32;
        float acc = 0.f;
        #pragma unroll 8
        for (int k = 0; k < 32; ++k) acc += w3p[k] * w2p[k * 32];
        qs[(size_t)oi * 32 + h] = (_Float16)(0.505f * lw[oi] * acc);
    } else if (tid < 659456) {
        // rbias[oi] = .505*lw*sum_k w3_k*b2_k
        const int oi = tid - 655360;
        const float* w3p = W3 + (size_t)oi * 32;
        const float* b2p = b2 + (size_t)oi * 32;
        float acc = 0.f;
        #pragma unroll 8
        for (int k = 0; k < 32; ++k) acc += w3p[k] * b2p[k];
        rb[oi] = 0.505f * lw[oi] * acc;
    } else if (tid < 675840) {
        // x -> duplicated f16 pairs
        const int j = tid - 659456;
        const int fe = j * 4;
        float4 xv = *(const float4*)(x + fe);
        uint4 p = { pkrtz(xv.x, xv.x), pkrtz(xv.y, xv.y),
                    pkrtz(xv.z, xv.z), pkrtz(xv.w, xv.w) };
        *(uint4*)(xd + fe) = p;
    } else if (tid < 692224) {
        // W1 -> f16
        const int j = tid - 675840;
        const float* s = W1 + (size_t)j * 8;
        float4 a = *(const float4*)s, c = *(const float4*)(s + 4);
        uint4 p = { pkrtz(a.x, a.y), pkrtz(a.z, a.w),
                    pkrtz(c.x, c.y), pkrtz(c.z, c.w) };
        *(uint4*)(w1h + (size_t)j * 8) = p;
    } else if (tid < 708608) {
        // b1 -> f16
        const int j = tid - 692224;
        const float* s = b1 + (size_t)j * 8;
        float4 a = *(const float4*)s, c = *(const float4*)(s + 4);
        uint4 p = { pkrtz(a.x, a.y), pkrtz(a.z, a.w),
                    pkrtz(c.x, c.y), pkrtz(c.z, c.w) };
        *(uint4*)(b1h + (size_t)j * 8) = p;
    } else if (tid < 724992) {
        // wbp[oi*32+k] = pk(.495*lw*w3, b2)
        const int j = tid - 708608;
        const int e = j * 8, oi = e >> 5;
        const float l = 0.495f * lw[oi];
        const float* w3g = W3 + e;
        const float* b2g = b2 + e;
        float4 wa = *(const float4*)(w3g), wb = *(const float4*)(w3g + 4);
        float4 ba = *(const float4*)(b2g), bb = *(const float4*)(b2g + 4);
        uint4 p0 = { pkrtz(l * wa.x, ba.x), pkrtz(l * wa.y, ba.y),
                     pkrtz(l * wa.z, ba.z), pkrtz(l * wa.w, ba.w) };
        uint4 p1 = { pkrtz(l * wb.x, bb.x), pkrtz(l * wb.y, bb.y),
                     pkrtz(l * wb.z, bb.z), pkrtz(l * wb.w, bb.w) };
        *(uint4*)(&wbp[e])     = p0;
        *(uint4*)(&wbp[e + 4]) = p1;
    }
}

// ================= main kernel (R18 loop verbatim, thin staging) =================
__global__ __launch_bounds__(256, 4)
void kan_kernel(const unsigned int* __restrict__ xd, const _Float16* __restrict__ w1h,
                const _Float16* __restrict__ b1h, const unsigned int* __restrict__ wbp,
                const _Float16* __restrict__ qsg, const float* __restrict__ rb,
                const float* __restrict__ b3,  const float* __restrict__ lw,
                const float* __restrict__ bw,  const _Float16* __restrict__ w2h,
                float* __restrict__ out)
{
    __shared__ unsigned int xsp[ROWS * XSTR];  // x dup-f16 pairs, 16.9 KB
    __shared__ _Float16 w1s[NI * H_];          // 4 KB
    __shared__ _Float16 b1s[NI * H_];          // 4 KB
    __shared__ unsigned int wbs[NI * H_];      // {.495*lw*w3, b2} f16 pairs, 8 KB
    __shared__ _Float16 qsl[NI * H_];          // q staged, 4 KB
    __shared__ float rcs[NWAVE][ROWS];         // per-seg row constants, 1 KB
    __shared__ float part[NWAVE][ROWS];        // per-wave i-slice partials, 1 KB

    const int t    = threadIdx.x;
    const int o    = blockIdx.x;               // o fastest -> same-o blocks share XCD
    const int row0 = blockIdx.y * ROWS;

    // ---- stage x tile: pure copy from pre-converted xd ----
    const unsigned int* xdp = xd + (size_t)row0 * NI;
    #pragma unroll
    for (int v = 0; v < 4; ++v) {
        int fe = (v * 256 + t) * 4;            // u32 index, multiple of 4
        int r = fe >> 6, c = fe & 63;
        uint4 w = *(const uint4*)(xdp + fe);
        uint2 lo = { w.x, w.y };
        uint2 hi = { w.z, w.w };
        *(uint2*)(&xsp[r * XSTR + c])     = lo;   // 66r+c even -> 8B aligned
        *(uint2*)(&xsp[r * XSTR + c + 2]) = hi;
    }
    // ---- stage W1/b1/wbs/q: pure copies ----
    *(uint4*)(w1s + t * 8) = *(const uint4*)(w1h + (size_t)o * (NI * H_) + t * 8);
    *(uint4*)(b1s + t * 8) = *(const uint4*)(b1h + (size_t)o * (NI * H_) + t * 8);
    {
        const unsigned int* wp = wbp + (size_t)o * (NI * H_ / 2) * 2; // o*2048
        *(uint4*)(&wbs[t * 8])     = *(const uint4*)(wp + t * 8);
        *(uint4*)(&wbs[t * 8 + 4]) = *(const uint4*)(wp + t * 8 + 4);
    }
    *(uint4*)(qsl + t * 8) = *(const uint4*)(qsg + (size_t)o * (NI * H_) + t * 8);
    __syncthreads();

    const int lane = t & 63, wave = t >> 6;
    const int col  = lane & 15;            // MFMA n-index (h2 k-slot) / A m-offset
    const int kh   = lane >> 4;            // contraction quad
    const int koff = kh * 8;
    const int i0   = wave * ISL;           // this wave's i-slice (16 wide)

    const halfx2 slope = { (_Float16)0.01f, (_Float16)0.01f };

    floatx4 pacc[MT];                      // |c| (negative-half) accumulators
    floatx4 acc1[MT];                      // q-MFMA (positive-half) accumulators
    #pragma unroll
    for (int m = 0; m < MT; ++m) {
        pacc[m] = floatx4{0.f, 0.f, 0.f, 0.f};
        acc1[m] = floatx4{0.f, 0.f, 0.f, 0.f};
    }

    // W2 f16 fragments: elem = (o*NI+i)*1024 + f*512 + lane*8
    const _Float16* wbase = w2h + (size_t)(o * NI + i0) * 1024 + (size_t)lane * 8;

    // prime the prefetch registers with iter 0's W2 fragments (R13 shape)
    halfx8 cA = *(const halfx8*)(wbase);
    halfx8 cB = *(const halfx8*)(wbase + 512);

    #pragma unroll 2
    for (int ii = 0; ii < ISL; ++ii) {
        const int i = i0 + ii;

        // issue next iteration's W2 loads before consuming this one's
        halfx8 nA, nB;
        if (ii < ISL - 1) {
            const _Float16* np = wbase + (ii + 1) * 1024;
            nA = *(const halfx8*)(np);
            nB = *(const halfx8*)(np + 512);
        }

        H8 w1v, b1v, qf;
        w1v.v8 = *(const halfx8*)(w1s + i * H_ + koff);
        b1v.v8 = *(const halfx8*)(b1s + i * H_ + koff);
        qf.v8  = *(const halfx8*)(qsl + i * H_ + koff);

        // per-k constants from LDS: {.495*lw*w3, b2} f16 pairs (broadcast reads)
        halfx2 q0 = __builtin_bit_cast(halfx2, wbs[i * H_ + col]);
        halfx2 q1 = __builtin_bit_cast(halfx2, wbs[i * H_ + col + 16]);
        float nn0 = (float)q0[0], b2c0 = (float)q0[1];
        float nn1 = (float)q1[0], b2c1 = (float)q1[1];

        #pragma unroll
        for (int m = 0; m < MT; ++m) {
            halfx2 xx = __builtin_bit_cast(halfx2, xsp[(m * 16 + col) * XSTR + i]);
            H8 af;
            #pragma unroll
            for (int j = 0; j < 4; ++j) {
                halfx2 h = __builtin_elementwise_fma(xx, w1v.v2[j], b1v.v2[j]);
                af.v2[j] = __builtin_elementwise_max(h, h * slope);  // pk leaky
            }
            floatx4 c0 = { b2c0, b2c0, b2c0, b2c0 };   // b2 folded into C
            floatx4 c1 = { b2c1, b2c1, b2c1, b2c1 };
            c0 = __builtin_amdgcn_mfma_f32_16x16x32_f16(af.v8, cA, c0, 0, 0, 0);
            c1 = __builtin_amdgcn_mfma_f32_16x16x32_f16(af.v8, cB, c1, 0, 0, 0);
            acc1[m] = __builtin_amdgcn_mfma_f32_16x16x32_f16(af.v8, qf.v8, acc1[m], 0, 0, 0);
            // negative-half epilogue only: pacc += (.495*lw*w3)*|c|
            #pragma unroll
            for (int r = 0; r < 4; ++r)
                pacc[m][r] = fmaf(nn0, fabsf(c0[r]),
                             fmaf(nn1, fabsf(c1[r]), pacc[m][r]));
        }

        cA = nA; cB = nB;
    }

    // ---- in-wave reduce over the 16 col lanes, deposit i-slice partials ----
    // acc1 columns are identical (broadcast B) -> add once at col==0, no reduce.
    #pragma unroll
    for (int m = 0; m < MT; ++m) {
        #pragma unroll
        for (int r = 0; r < 4; ++r) {
            float v = pacc[m][r];
            v += __shfl_xor(v, 1, 64);
            v += __shfl_xor(v, 2, 64);
            v += __shfl_xor(v, 4, 64);
            v += __shfl_xor(v, 8, 64);
            if (col == 0)
                part[wave][m * 16 + kh * 4 + r] = v + acc1[m][r];  // C row = kh*4+r
        }
    }

    // ---- per-row constants, 4-way parallel over i-segments ----
    {
        const int row = t & 63, seg = t >> 6;
        float s = 0.f;
        const float* bwp = bw + o * NI;
        const float* lp  = lw + o * NI;
        const float* b3p = b3 + o * NI;
        const float* rbp = rb + o * NI;
        #pragma unroll
        for (int u = 0; u < NI / NWAVE; ++u) {
            int i = seg * (NI / NWAVE) + u;
            halfx2 hx = __builtin_bit_cast(halfx2, xsp[row * XSTR + i]);
            s += bwp[i] * leaky((float)hx[0]) + lp[i] * b3p[i] + rbp[i];
        }
        rcs[seg][row] = s;
    }
    __syncthreads();

    // ---- cross-wave sum + per-row constants, write out[b,o] ----
    if (t < ROWS) {
        float v = 0.f;
        #pragma unroll
        for (int w = 0; w < NWAVE; ++w) v += part[w][t] + rcs[w][t];
        out[(size_t)(row0 + t) * NO + o] = v;
    }
}

// ================= fallback (R16 verbatim, no workspace) =================
__global__ __launch_bounds__(256, 6)
void kan_fb(const float* __restrict__ x,  const float* __restrict__ W1,
            const float* __restrict__ b1, const float* __restrict__ W2,
            const float* __restrict__ b2, const float* __restrict__ W3,
            const float* __restrict__ b3, const float* __restrict__ lw,
            const float* __restrict__ bw, float* __restrict__ out)
{
    __shared__ unsigned int xsp[32 * XSTR];
    __shared__ _Float16 w1s[NI * H_];
    __shared__ _Float16 b1s[NI * H_];
    __shared__ unsigned int wbs[NI * H_];
    __shared__ float rcs[8][32];
    __shared__ float part[4][32];

    const int t    = threadIdx.x;
    const int o    = blockIdx.x;
    const int row0 = blockIdx.y * 32;

    const float* xsrc = x + (size_t)row0 * NI;
    #pragma unroll
    for (int v = 0; v < 2; ++v) {
        int fe = (v * 256 + t) * 4;
        int r = fe >> 6, c = fe & 63;
        float4 xv = *(const float4*)(xsrc + fe);
        uint2 lo = { pkrtz(xv.x, xv.x), pkrtz(xv.y, xv.y) };
        uint2 hi = { pkrtz(xv.z, xv.z), pkrtz(xv.w, xv.w) };
        *(uint2*)(&xsp[r * XSTR + c])     = lo;
        *(uint2*)(&xsp[r * XSTR + c + 2]) = hi;
    }
    const float* w1g = W1 + (size_t)o * NI * H_;
    const float* b1g = b1 + (size_t)o * NI * H_;
    #pragma unroll
    for (int v = 0; v < 2; ++v) {
        int e = (v * 256 + t) * 4;
        float4 a = *(const float4*)(w1g + e);
        float4 c = *(const float4*)(b1g + e);
        uint2 pa = { pkrtz(a.x, a.y), pkrtz(a.z, a.w) };
        uint2 pc = { pkrtz(c.x, c.y), pkrtz(c.z, c.w) };
        *(uint2*)(w1s + e) = pa;
        *(uint2*)(b1s + e) = pc;
    }
    {
        int e = t * 8;
        float l = lw[o * NI + (e >> 5)];
        const float* w3g = W3 + (size_t)o * NI * H_ + e;
        const float* b2g = b2 + (size_t)o * NI * H_ + e;
        float4 wa = *(const float4*)(w3g), wb = *(const float4*)(w3g + 4);
        float4 ba = *(const float4*)(b2g), bb = *(const float4*)(b2g + 4);
        uint4 p0 = { pkrtz(l * wa.x, ba.x), pkrtz(l * wa.y, ba.y),
                     pkrtz(l * wa.z, ba.z), pkrtz(l * wa.w, ba.w) };
        uint4 p1 = { pkrtz(l * wb.x, bb.x), pkrtz(l * wb.y, bb.y),
                     pkrtz(l * wb.z, bb.z), pkrtz(l * wb.w, bb.w) };
        *(uint4*)(&wbs[e])     = p0;
        *(uint4*)(&wbs[e + 4]) = p1;
    }
    __syncthreads();

    const int lane = t & 63, wave = t >> 6;
    const int col  = lane & 15;
    const int kh   = lane >> 4;
    const int koff = kh * 8;
    const int i0   = wave * 16;

    const float* w2p0 = W2 + ((size_t)(o * NI + i0) * H_ + col) * H_ + koff;
    const float* w2p1 = w2p0 + 16 * H_;
    const halfx2 slope = { (_Float16)0.01f, (_Float16)0.01f };

    floatx4 pacc[2];
    #pragma unroll
    for (int m = 0; m < 2; ++m) pacc[m] = floatx4{0.f, 0.f, 0.f, 0.f};

    floatx4 a0 = *(const floatx4*)(w2p0);
    floatx4 a1 = *(const floatx4*)(w2p0 + 4);
    floatx4 a2 = *(const floatx4*)(w2p1);
    floatx4 a3 = *(const floatx4*)(w2p1 + 4);

    #pragma unroll 2
    for (int ii = 0; ii < 16; ++ii) {
        const int i = i0 + ii;
        floatx4 n0, n1, n2, n3;
        if (ii < 15) {
            const float* np0 = w2p0 + (ii + 1) * (H_ * H_);
            const float* np1 = w2p1 + (ii + 1) * (H_ * H_);
            n0 = *(const floatx4*)(np0);
            n1 = *(const floatx4*)(np0 + 4);
            n2 = *(const floatx4*)(np1);
            n3 = *(const floatx4*)(np1 + 4);
        }
        H8 bf0, bf1;
        bf0.u[0] = pkrtz(a0[0], a0[1]);  bf0.u[1] = pkrtz(a0[2], a0[3]);
        bf0.u[2] = pkrtz(a1[0], a1[1]);  bf0.u[3] = pkrtz(a1[2], a1[3]);
        bf1.u[0] = pkrtz(a2[0], a2[1]);  bf1.u[1] = pkrtz(a2[2], a2[3]);
        bf1.u[2] = pkrtz(a3[0], a3[1]);  bf1.u[3] = pkrtz(a3[2], a3[3]);
        H8 w1v, b1v;
        w1v.v8 = *(const halfx8*)(w1s + i * H_ + koff);
        b1v.v8 = *(const halfx8*)(b1s + i * H_ + koff);
        halfx2 q0 = __builtin_bit_cast(halfx2, wbs[i * H_ + col]);
        halfx2 q1 = __builtin_bit_cast(halfx2, wbs[i * H_ + col + 16]);
        float w3e0 = (float)q0[0], b2c0 = (float)q0[1];
        float w3e1 = (float)q1[0], b2c1 = (float)q1[1];
        float p0 = 0.505f * w3e0, nn0 = 0.495f * w3e0;
        float p1 = 0.505f * w3e1, nn1 = 0.495f * w3e1;
        #pragma unroll
        for (int m = 0; m < 2; ++m) {
            halfx2 xx = __builtin_bit_cast(halfx2, xsp[(m * 16 + col) * XSTR + i]);
            H8 af;
            #pragma unroll
            for (int j = 0; j < 4; ++j) {
                halfx2 h = __builtin_elementwise_fma(xx, w1v.v2[j], b1v.v2[j]);
                af.v2[j] = __builtin_elementwise_max(h, h * slope);
            }
            floatx4 c0 = { b2c0, b2c0, b2c0, b2c0 };
            floatx4 c1 = { b2c1, b2c1, b2c1, b2c1 };
            c0 = __builtin_amdgcn_mfma_f32_16x16x32_f16(af.v8, bf0.v8, c0, 0, 0, 0);
            c1 = __builtin_amdgcn_mfma_f32_16x16x32_f16(af.v8, bf1.v8, c1, 0, 0, 0);
            #pragma unroll
            for (int r = 0; r < 4; ++r) {
                float acc = pacc[m][r];
                acc = fmaf(p0,  c0[r],
                      fmaf(nn0, fabsf(c0[r]),
                      fmaf(p1,  c1[r],
                      fmaf(nn1, fabsf(c1[r]), acc))));
                pacc[m][r] = acc;
            }
        }
        a0 = n0; a1 = n1; a2 = n2; a3 = n3;
    }
    #pragma unroll
    for (int m = 0; m < 2; ++m) {
        #pragma unroll
        for (int r = 0; r < 4; ++r) {
            float v = pacc[m][r];
            v += __shfl_xor(v, 1, 64);
            v += __shfl_xor(v, 2, 64);
            v += __shfl_xor(v, 4, 64);
            v += __shfl_xor(v, 8, 64);
            if (col == 0)
                part[wave][m * 16 + kh * 4 + r] = v;
        }
    }
    {
        const int row = t & 31, seg = t >> 5;
        float s = 0.f;
        const float* bwp = bw + o * NI;
        const float* lp  = lw + o * NI;
        const float* b3p = b3 + o * NI;
        #pragma unroll
        for (int u = 0; u < 8; ++u) {
            int i = seg * 8 + u;
            halfx2 hx = __builtin_bit_cast(halfx2, xsp[row * XSTR + i]);
            s += bwp[i] * leaky((float)hx[0]) + lp[i] * b3p[i];
        }
        rcs[seg][row] = s;
    }
    __syncthreads();
    if (t < 32) {
        float v = 0.f;
        #pragma unroll
        for (int w = 0; w < 4; ++w) v += part[w][t];
        #pragma unroll
        for (int s = 0; s < 8; ++s) v += rcs[s][t];
        out[(size_t)(row0 + t) * NO + o] = v;
    }
}

extern "C" void kernel_launch(void* const* d_in, const int* in_sizes, int n_in,
                              void* d_out, int out_size, void* d_ws, size_t ws_size,
                              hipStream_t stream) {
    const float* x  = (const float*)d_in[0];
    const float* W1 = (const float*)d_in[1];
    const float* b1 = (const float*)d_in[2];
    const float* W2 = (const float*)d_in[3];
    const float* b2 = (const float*)d_in[4];
    const float* W3 = (const float*)d_in[5];
    const float* b3 = (const float*)d_in[6];
    const float* lw = (const float*)d_in[7];
    const float* bw = (const float*)d_in[8];
    float* out = (float*)d_out;

    if (d_ws && ws_size >= (size_t)WS_NEED) {
        char* w = (char*)d_ws;
        _Float16*     w2h = (_Float16*)(w + W2H_OFF);
        _Float16*     qsg = (_Float16*)(w + QS_OFF);
        float*        rb  = (float*)(w + RB_OFF);
        unsigned int* xd  = (unsigned int*)(w + XD_OFF);
        _Float16*     w1h = (_Float16*)(w + W1H_OFF);
        _Float16*     b1h = (_Float16*)(w + B1H_OFF);
        unsigned int* wbp = (unsigned int*)(w + WBP_OFF);
        kan_pre<<<dim3(2832), dim3(256), 0, stream>>>(x, W1, b1, W2, b2, W3, lw,
                                                      w2h, qsg, rb, xd, w1h, b1h, wbp);
        dim3 grid(NO, NB / ROWS);   // 1024 blocks, o fastest (XCD-local), 4/CU
        kan_kernel<<<grid, dim3(256), 0, stream>>>(xd, w1h, b1h, wbp, qsg, rb,
                                                   b3, lw, bw, w2h, out);
    } else {
        dim3 grid(NO, NB / 32);     // fallback: R16 config
        kan_fb<<<grid, dim3(256), 0, stream>>>(x, W1, b1, W2, b2, W3, b3, lw, bw, out);
    }
}